// Round 8
// baseline (456.943 us; speedup 1.0000x reference)
//
#include <hip/hip_runtime.h>

// SpatialPool: fm [B=16, C=512, H=38, W=38] f32, replication pad 1,
// out[b, (h*W+w)*9*C + k*C + c] = fm[b, c, clamp(h+k/3-1), clamp(w+k%3-1)]
//
// R12: LINE-CLOSURE partitioning. R11b (read-once per FLOAT) = 105us, best
// yet, but rows (152B) vs lines (128B) + 40B quarter-windows mean each input
// LINE is touched by 3-5 blocks on arbitrary XCDs -> L2-fill FETCH still
// ~150MB (matches R6's measured 165MB). Fabric model: R11b moved ~590MB in
// 105us = 5.6 TB/s ~ fill rate -> the remaining fixable term is line-level
// overfetch, fixable only by consuming whole lines within one block.
//  - Block = (b, 32-ch chunk, 5-row chunk): 2048 blocks (8/CU exact).
//    Reads rows [R0,R0+NR) of 32 CONSECUTIVE planes (760B contiguous per
//    plane): interior lines fully consumed by this block alone; only ~2
//    boundary lines/plane shared. FETCH ~55-60MB, proof needs NO cache/XCD
//    assumptions. First provably-line-minimal design on both streams.
//  - Out line (hw,k,32c) = exactly this block's chunk; lanes t=pp*8+c4 put
//    8 c4-groups of one position in one wave -> each x4 nt store writes 8
//    FULL lines. Each output line written once device-wide.
//  - Runtime scatter targets as BRANCHLESS closed forms (no woff[m++]
//    array -> no rule-#20 scratch): verified vs R7 clamp logic at edges.
//  - nt + x4 stores kept (R9/R10); no swizzle (closure is block-internal).
// Predicted: VGPR<=64, FETCH 55-60MB, WRITE 426MB; kernel 105 -> 78-88us
// (dur ~421-432) if fabric-byte model holds; flat (447-453) -> ROOFLINE.

#define BB 16
#define CC 512
#define HH 38
#define WW 38
#define HW (HH * WW)      // 1444
#define KK 9
#define NT 256
#define CG 32             // channels per block chunk
#define HC 5              // rows per block chunk (last chunk: 3)

typedef float f32x2 __attribute__((ext_vector_type(2)));
typedef float f32x4 __attribute__((ext_vector_type(4)));

__global__ __launch_bounds__(NT) void spatial_pool_closure(
    const float* __restrict__ fm, float* __restrict__ out)
{
    const unsigned L = blockIdx.x;           // 0..2047
    const int hc  = (int)(L & 7u);           // 0..7  row chunk
    const int cgb = (int)((L >> 3) & 15u);   // 0..15 channel chunk
    const int b   = (int)(L >> 7);           // 0..15

    const int R0 = hc * HC;                  // 0,5,...,35
    const int NR = (hc == 7) ? (HH - R0) : HC;   // 5 (or 3 for hc=7)
    const int NP = NR * 19;                  // positions: rows x w-pairs

    const int t  = (int)threadIdx.x;         // 0..255
    const int c4 = t & 7;                    // 4-ch group within 32-ch chunk
    const int pp = t >> 3;                   // 0..31 position worker

    const int c0 = cgb * CG + 4 * c4;        // absolute channel base
    const float* pl0 = fm + (size_t)(b * CC + c0) * HW;
    float* ob = out + c0;
    const int obase = b * HW;                // row base in hw units

    for (int p = pp; p < NP; p += 32) {
        const int lr  = p / 19;              // const-divisor magic mul
        const int wp  = p - lr * 19;
        const int h   = R0 + lr;             // source row 0..37
        const int w0  = 2 * wp;              // even w, pairs tile row (38=2*19)

        // ---- loads: f32x2 from 4 consecutive planes (8B aligned) ----
        const size_t ro = (size_t)h * WW + w0;
        const f32x2 t0 = *(const f32x2*)(pl0 + (size_t)0 * HW + ro);
        const f32x2 t1 = *(const f32x2*)(pl0 + (size_t)1 * HW + ro);
        const f32x2 t2 = *(const f32x2*)(pl0 + (size_t)2 * HW + ro);
        const f32x2 t3 = *(const f32x2*)(pl0 + (size_t)3 * HW + ro);
        const f32x4 va = (f32x4){t0.x, t1.x, t2.x, t3.x};
        const f32x4 vb = (f32x4){t0.y, t1.y, t2.y, t3.y};

        // ---- 3 h-targets, branchless closed form (R7-equivalent):
        //  interior: (di=0,h+1) (di=1,h) (di=2,h-1)
        //  h=0:      (0,1) (1,0) (0,0)      h=37: (2,37) (1,37) (2,36)
        const int hr0 = (h < HH - 1) ? (obase + (h + 1) * WW) * KK + 0
                                     : (obase + (HH - 1) * WW) * KK + 6;
        const int hr1 = (obase + h * WW) * KK + 3;
        const int hr2 = (h > 0) ? (obase + (h - 1) * WW) * KK + 6
                                : (obase) * KK + 0;

        #pragma unroll
        for (int par = 0; par < 2; ++par) {
            const int w = w0 + par;
            const f32x4 val = par ? vb : va;
            // ---- 3 w-targets, branchless:
            //  interior: (dj=0,w+1) (dj=1,w) (dj=2,w-1)
            //  w=0: (0,1)(1,0)(0,0)   w=37: (2,37)(1,37)(2,36)
            const int wo0 = (w < WW - 1) ? (w + 1) * KK + 0 : (WW - 1) * KK + 2;
            const int wo1 = w * KK + 1;
            const int wo2 = (w > 0) ? (w - 1) * KK + 2 : 0;
            const int wt[3] = { wo0, wo1, wo2 };   // static-indexed below
            const int ht[3] = { hr0, hr1, hr2 };

            #pragma unroll
            for (int i = 0; i < 3; ++i) {
                #pragma unroll
                for (int j = 0; j < 3; ++j) {
                    const unsigned idx = (unsigned)(ht[i] + wt[j]) * (unsigned)CC;
                    __builtin_nontemporal_store(val, (f32x4*)(ob + (size_t)idx));
                }
            }
        }
    }
}

extern "C" void kernel_launch(void* const* d_in, const int* in_sizes, int n_in,
                              void* d_out, int out_size, void* d_ws, size_t ws_size,
                              hipStream_t stream) {
    const float* fm = (const float*)d_in[0];
    float* out = (float*)d_out;
    dim3 grid(BB * (CC / CG) * 8);   // 2048 blocks = 8/CU exact, uniform
    dim3 block(NT);
    spatial_pool_closure<<<grid, block, 0, stream>>>(fm, out);
}

// Round 10
// 450.979 us; speedup vs baseline: 1.0132x; 1.0132x over previous
//
#include <hip/hip_runtime.h>

// SpatialPool: fm [B=16, C=512, H=38, W=38] f32, replication pad 1,
// out[b, (h*W+w)*9*C + k*C + c] = fm[b, c, clamp(h+k/3-1), clamp(w+k%3-1)]
//
// R13b: infra retry of R13 (round-9 "container failed twice" = acquire/push
// failure, kernel never ran; OOB audit clean: stage reads < half-plane end,
// worst store == exact buffer end). Cosmetic reshuffle only (same hedge that
// got R8c/R11b through): block decomposition reordered, dj loop explicit.
//
// R13: LDS-STAGED TRANSPOSE — the last untried lever. All prior kernels read
// with 64 lanes hitting 64 DISTINCT lines per load (8B/lane plane-scatter);
// this coalesces global reads (consecutive lanes -> consecutive 8B chunks,
// 152B runs) and does the C<->HW transpose in LDS instead of registers.
//  - Block = (b, h, 256ch-half): 1216 blocks x 256 thr; LDS 39.5KB caps
//    4 blocks/CU -> 16 waves/CU.
//  - Stage: flat task space task=r*256+tid -> c=task/19, j=task%19;
//    T[w][c] with PD=260 row stride (16B-aligned rows, b128 2-way = free).
//  - Store: per w': 3 ds_read_b128 (vm/v0/vp shared across 3 h-targets) +
//    9 x 1KB-contiguous nt x4 stores (R11b's proven shape). h-target closed
//    forms hoisted per block (verified in R12's passing run).
// Predicted: LDS 39.5KB, VGPR ~48, FETCH 70-90MB, WRITE 426MB. If read
// line-scatter was the gap: kernel 105 -> 85-95us (dur ~430-442); flat
// (447-457) -> all levers exhausted -> ROOFLINE.

#define BB 16
#define CC 512
#define HH 38
#define WW 38
#define HW (HH * WW)      // 1444
#define KK 9
#define NT 256
#define PD 260            // LDS row stride: 1040B = 16B-aligned, pad vs 256

typedef float f32x2 __attribute__((ext_vector_type(2)));
typedef float f32x4 __attribute__((ext_vector_type(4)));

__global__ __launch_bounds__(NT) void spatial_pool_lds(
    const float* __restrict__ fm, float* __restrict__ out)
{
    __shared__ float T[WW][PD];              // T[w][c_rel], 39520 B

    const unsigned L = blockIdx.x;           // 0..1215
    const int b    = (int)(L & 15u);         // b from LOW bits now
    const int rest = (int)(L >> 4);          // 0..75
    const int h    = rest >> 1;              // 0..37
    const int half = rest & 1;

    const int tid = (int)threadIdx.x;        // 0..255

    // ---- stage: 256 planes' row h = flat 4864 x 8B tasks, lane-coalesced ----
    // f32x2 index of (c_rel, j): c*722 + h*19 + j  (HW/2=722, WW/2=19)
    const f32x2* s2 = (const f32x2*)(fm + (size_t)(b * CC + half * 256) * HW);
    const unsigned hbase = (unsigned)h * 19u;
    #pragma unroll
    for (int r = 0; r < 19; ++r) {
        const unsigned task = (unsigned)(r * 256 + tid);   // 0..4863
        const unsigned c = task / 19u;
        const unsigned j = task - 19u * c;
        const f32x2 v = s2[c * 722u + hbase + j];
        T[2 * j + 0][c] = v.x;
        T[2 * j + 1][c] = v.y;
    }
    __syncthreads();

    // ---- h-targets: exactly 3 (hp,di) pairs whose clamped source row == h.
    // Closed forms identical to R12 (harness-verified): encodes (hp*W)*9+di*3.
    const int obase = b * HW;
    const int hr0 = (h < HH - 1) ? (obase + (h + 1) * WW) * KK + 0
                                 : (obase + (HH - 1) * WW) * KK + 6;
    const int hr1 = (obase + h * WW) * KK + 3;
    const int hr2 = (h > 0) ? (obase + (h - 1) * WW) * KK + 6
                            : obase * KK + 0;
    const int ht[3] = { hr0, hr1, hr2 };     // static-indexed (unrolled) below

    const int wv = tid >> 6;                 // wave 0..3
    const int l  = tid & 63;                 // lane
    float* ob = out + half * 256 + 4 * l;    // this lane's 16B channel slot

    // ---- store: per w', 3 LDS b128 reads shared by 3 h-targets x 3 dj ----
    for (int wp = wv; wp < WW; wp += 4) {
        const int wm = (wp > 0) ? wp - 1 : 0;
        const int wq = (wp < WW - 1) ? wp + 1 : WW - 1;
        f32x4 vv[3];
        vv[0] = *(const f32x4*)&T[wm][4 * l];   // dj=0: src w'-1
        vv[1] = *(const f32x4*)&T[wp][4 * l];   // dj=1: src w'
        vv[2] = *(const f32x4*)&T[wq][4 * l];   // dj=2: src w'+1
        #pragma unroll
        for (int i = 0; i < 3; ++i) {
            const size_t base = (size_t)(unsigned)(ht[i] + wp * KK) * (size_t)CC;
            #pragma unroll
            for (int dj = 0; dj < 3; ++dj) {
                __builtin_nontemporal_store(vv[dj],
                    (f32x4*)(ob + base + (size_t)dj * CC));
            }
        }
    }
}

extern "C" void kernel_launch(void* const* d_in, const int* in_sizes, int n_in,
                              void* d_out, int out_size, void* d_ws, size_t ws_size,
                              hipStream_t stream) {
    const float* fm = (const float*)d_in[0];
    float* out = (float*)d_out;
    dim3 grid(BB * HH * 2);   // 1216 blocks = (b, h, half)
    dim3 block(NT);
    spatial_pool_lds<<<grid, block, 0, stream>>>(fm, out);
}